// Round 7
// baseline (61.582 us; speedup 1.0000x reference)
//
#include <hip/hip_runtime.h>

typedef _Float16 half8 __attribute__((ext_vector_type(8)));
typedef float f32x16 __attribute__((ext_vector_type(16)));

#define SLOT 55296               // 54 frags * 1KB
#define LDS_TOTAL (2 * SLOT)     // 110592 B, double-buffered B only

// async global->LDS, 16B/lane; dest is the WAVE-UNIFORM base (HW adds lane*16)
__device__ __forceinline__ void stage16(const void* g, const void* l) {
  __builtin_amdgcn_global_load_lds(
      (const __attribute__((address_space(1))) unsigned int*)(unsigned long long)g,
      (__attribute__((address_space(3))) unsigned int*)(unsigned int)(unsigned long long)l,
      16, 0, 0);
}

// ---------------------------------------------------------------------------
// Pre-pack W [55,64,64] f32 -> f16 MFMA B-fragments, order [nt][ks][cc][l]:
// frag f = ((nt*2+ks)*2 + cc)*54 + l ; elem e = lane*8 + v ;
// value = W[l, (ks*2+cc)*16 + (lane>>5)*8 + v, nt*32 + (lane&31)].
// Bias row (l=54) folded to f32[64] at byte offset 442368.
// ---------------------------------------------------------------------------
__global__ __launch_bounds__(256)
void prepack_kernel(const float* __restrict__ W, _Float16* __restrict__ Bp) {
  const int idx = blockIdx.x * 256 + threadIdx.x;
  if (idx < 221184) {                    // 432 frags * 512 elems
    const int v   = idx & 7;
    const int lam = (idx >> 3) & 63;
    const int f   = idx >> 9;
    const int l   = f % 54;
    const int r   = f / 54;
    const int cc  = r & 1;
    const int ks  = (r >> 1) & 1;
    const int nt  = (r >> 2) & 1;
    const int c   = (ks * 2 + cc) * 16 + (lam >> 5) * 8 + v;
    const int o   = nt * 32 + (lam & 31);
    Bp[idx] = (_Float16)W[(l * 64 + c) * 64 + o];
  } else if (idx < 221184 + 64) {
    const int o = idx - 221184;
    float s = 0.f;
    for (int c = 0; c < 64; ++c) s += W[(54 * 64 + c) * 64 + o];
    ((float*)(Bp + 221184))[o] = s;
  }
}

// ---------------------------------------------------------------------------
// Grid 256 = 1 block/CU: 128 row-groups (8 rows of one image) x 2 nt.
// Block = 512 thr = 8 waves (2/SIMD); wave w = image row r0+w: M=64
// (2 m-tiles of 32), N=32. K = 4 phases (ks x cc, 16 ch each) x 54 l.
// LDS holds ONLY B: 2 x 54KB slots, ping-pong, staged via global_load_lds
// during the previous phase's compute. Taps read f32 straight from L2
// (x is L3-resident; no x-tile, no tap LDS traffic). acc in regs throughout.
// ---------------------------------------------------------------------------
__global__ __launch_bounds__(512, 2)
void qconv_kernel(const float* __restrict__ x, const _Float16* __restrict__ Bp,
                  float* __restrict__ out) {
  constexpr int IU[45] = {0,0,0,0,0,0,0,0,0, 1,1,1,1,1,1,1,1, 2,2,2,2,2,2,2,
                          3,3,3,3,3,3, 4,4,4,4,4, 5,5,5,5, 6,6,6, 7,7, 8};
  constexpr int JU[45] = {0,1,2,3,4,5,6,7,8, 1,2,3,4,5,6,7,8, 2,3,4,5,6,7,8,
                          3,4,5,6,7,8, 4,5,6,7,8, 5,6,7,8, 6,7,8, 7,8, 8};

  const int tid  = threadIdx.x;
  const int wave = tid >> 6;          // 0..7 -> image row r0+wave
  const int lane = tid & 63;
  const int colA = lane & 31;
  const int kg   = lane >> 5;

  // XCD-aware remap: 32 blocks/XCD cover 2 images (x slice L2-resident)
  const int phys = blockIdx.x;
  const int xcd  = phys & 7;
  const int slot = phys >> 3;              // 0..31
  const int g    = xcd * 16 + (slot >> 1); // row-group 0..127
  const int nt   = slot & 1;
  const int b    = g >> 3;
  const int r0   = (g & 7) * 8;
  const int r    = r0 + wave;              // this wave's image row

  __shared__ __align__(16) unsigned char smem[LDS_TOTAL];
  const char* BpB = (const char*)Bp;

  // ---- prologue: stage phase-0 B slice into slot 0 (7 frags/wave, clamped)
  {
    const size_t src = (size_t)((nt * 2 + 0) * 2 + 0) * SLOT;
#pragma unroll
    for (int q = 0; q < 7; ++q) {
      const int f = min(wave * 7 + q, 53);
      stage16(BpB + src + (size_t)f * 1024 + lane * 16,
              (char*)smem + 0 * SLOT + f * 1024);
    }
  }
  __syncthreads();                    // drains vmcnt(0), slot 0 visible

  f32x16 acc[2] = {};

  for (int p = 0; p < 4; ++p) {       // phase = (ks, cc) 16-ch chunk
    const int ks = p >> 1;
    const int cc = p & 1;
    const int chb = (ks * 2 + cc) * 16 + kg * 8;   // this lane's 8 channels

    // ---- 1) tap loads: f32 direct from global (L2-hot), issued first ----
    half8 tap[2][9];
#pragma unroll
    for (int mt = 0; mt < 2; ++mt) {
      float4 tlo[9], thi[9];
#pragma unroll
      for (int t = 0; t < 9; ++t) {
        const int rr = r + t / 3 - 1;
        const int cl = mt * 32 + colA + (t % 3) - 1;
        float4 z = make_float4(0.f, 0.f, 0.f, 0.f);
        tlo[t] = z; thi[t] = z;
        if ((unsigned)rr < 64u && (unsigned)cl < 64u) {
          const float* pa = x + ((((size_t)b * 64 + rr) * 64 + cl) * 64 + chb);
          tlo[t] = *(const float4*)pa;
          thi[t] = *(const float4*)(pa + 4);
        }
      }
#pragma unroll
      for (int t = 0; t < 9; ++t) {
        half8 hv;
        hv[0] = (_Float16)tlo[t].x; hv[1] = (_Float16)tlo[t].y;
        hv[2] = (_Float16)tlo[t].z; hv[3] = (_Float16)tlo[t].w;
        hv[4] = (_Float16)thi[t].x; hv[5] = (_Float16)thi[t].y;
        hv[6] = (_Float16)thi[t].z; hv[7] = (_Float16)thi[t].w;
        tap[mt][t] = hv;
      }
    }

    // ---- 2) stage NEXT phase's B slice into the other slot (after taps,
    //         so the compiler's tap-wait is a counted vmcnt, not a drain) ---
    asm volatile("" ::: "memory");    // pin issue order: taps before stages
    if (p < 3) {
      const int pn = p + 1;
      const size_t src = (size_t)((nt * 2 + (pn >> 1)) * 2 + (pn & 1)) * SLOT;
#pragma unroll
      for (int q = 0; q < 7; ++q) {
        const int f = min(wave * 7 + q, 53);
        stage16(BpB + src + (size_t)f * 1024 + lane * 16,
                (char*)smem + (pn & 1) * SLOT + f * 1024);
      }
    }

    // ---- 3) compute: 54 l-steps, depth-8 B-frag prefetch, 2 MFMA each ----
    const unsigned sbase = (p & 1) * SLOT + lane * 16;
    half8 bq[8];
#pragma unroll
    for (int q = 0; q < 8; ++q)
      bq[q] = *(const half8*)(smem + sbase + q * 1024);
#pragma unroll
    for (int l = 0; l < 54; ++l) {
      const half8 bf = bq[l & 7];
      if (l + 8 < 54)                 // compile-time after unroll
        bq[l & 7] = *(const half8*)(smem + sbase + (l + 8) * 1024);
      half8 a0, a1;
      if (l < 45) {
        a0 = tap[0][IU[l]] * tap[0][JU[l]];   // v_pk_mul_f16 x4
        a1 = tap[1][IU[l]] * tap[1][JU[l]];
      } else {
        a0 = tap[0][l - 45];
        a1 = tap[1][l - 45];
      }
      acc[0] = __builtin_amdgcn_mfma_f32_32x32x16_f16(a0, bf, acc[0], 0, 0, 0);
      acc[1] = __builtin_amdgcn_mfma_f32_32x32x16_f16(a1, bf, acc[1], 0, 0, 0);
    }

    __syncthreads();                  // stages landed (issued a phase ago)
  }

  // ---- epilogue: bias + coalesced stores ---------------------------------
  const float bias = ((const float*)(BpB + 442368))[nt * 32 + colA];
#pragma unroll
  for (int mt = 0; mt < 2; ++mt) {
    float* op = out + (((size_t)b * 64 + r) * 64 + mt * 32) * 64
                    + nt * 32 + colA;
#pragma unroll
    for (int gi = 0; gi < 16; ++gi) {
      const int rowD = (gi & 3) + 8 * (gi >> 2) + 4 * kg;  // pixel within mt
      op[(size_t)rowD * 64] = acc[mt][gi] + bias;
    }
  }
}

extern "C" void kernel_launch(void* const* d_in, const int* in_sizes, int n_in,
                              void* d_out, int out_size, void* d_ws, size_t ws_size,
                              hipStream_t stream) {
  const float* x = (const float*)d_in[0];
  const float* W = (const float*)d_in[1];
  float* out     = (float*)d_out;
  _Float16* Bp   = (_Float16*)d_ws;   // 442368 B frags + 256 B bias

  prepack_kernel<<<dim3((221248 + 255) / 256), dim3(256), 0, stream>>>(W, Bp);
  qconv_kernel<<<dim3(256), dim3(512), 0, stream>>>(x, Bp, out);
}

// Round 8
// 40.692 us; speedup vs baseline: 1.5134x; 1.5134x over previous
//
#include <hip/hip_runtime.h>

typedef _Float16 half8 __attribute__((ext_vector_type(8)));
typedef _Float16 half4v __attribute__((ext_vector_type(4)));
typedef float f32x16 __attribute__((ext_vector_type(16)));

#define BOFF 0                   // B-slice: 108 frags * 1KB = 110592 B
#define XOFF 110592              // x-tile: 10 rows * 66 cols * 32ch f16 = 42240 B
#define LDS_TOTAL 152832

// async global->LDS, 16B/lane; dest is the WAVE-UNIFORM base (HW adds lane*16)
__device__ __forceinline__ void stage16(const void* g, const void* l) {
  __builtin_amdgcn_global_load_lds(
      (const __attribute__((address_space(1))) unsigned int*)(unsigned long long)g,
      (__attribute__((address_space(3))) unsigned int*)(unsigned int)(unsigned long long)l,
      16, 0, 0);
}

// ---------------------------------------------------------------------------
// Pre-pack W [55,64,64] f32 -> f16 MFMA B-fragments, order [nt][ks][cc][l]:
// frag f = ((nt*2+ks)*2 + cc)*54 + l ; elem e = lane*8 + v ;
// value = W[l, (ks*2+cc)*16 + (lane>>5)*8 + v, nt*32 + (lane&31)].
// Bias row (l=54) folded to f32[64] at byte offset 442368.
// ---------------------------------------------------------------------------
__global__ __launch_bounds__(256)
void prepack_kernel(const float* __restrict__ W, _Float16* __restrict__ Bp) {
  const int idx = blockIdx.x * 256 + threadIdx.x;
  if (idx < 221184) {                    // 432 frags * 512 elems
    const int v   = idx & 7;
    const int lam = (idx >> 3) & 63;
    const int f   = idx >> 9;
    const int l   = f % 54;
    const int r   = f / 54;
    const int cc  = r & 1;
    const int ks  = (r >> 1) & 1;
    const int nt  = (r >> 2) & 1;
    const int c   = (ks * 2 + cc) * 16 + (lam >> 5) * 8 + v;
    const int o   = nt * 32 + (lam & 31);
    Bp[idx] = (_Float16)W[(l * 64 + c) * 64 + o];
  } else if (idx < 221184 + 64) {
    const int o = idx - 221184;
    float s = 0.f;
    for (int c = 0; c < 64; ++c) s += W[(54 * 64 + c) * 64 + o];
    ((float*)(Bp + 221184))[o] = s;
  }
}

// ---------------------------------------------------------------------------
// Persistent-B kernel, 8 waves (2/SIMD), grid 256 = 1 block/CU.
// 128 row-groups (8 rows of one image) x 2 nt. Wave w = image row r0+w:
// M=64 (2 m-tiles of 32), N=32 (nt). B-slice (nt,ks) = 108 KB LDS-resident;
// two temporal ks-rounds, acc in regs across rounds. Latency engineering:
// depth-6 B-frag prefetch (covers ~120cy LDS latency), cc=1 taps trickled in
// during cc=0's MFMA loop, setprio around the MFMA pair.
// ---------------------------------------------------------------------------
__global__ __launch_bounds__(512, 2)
void qconv_kernel(const float* __restrict__ x, const _Float16* __restrict__ Bp,
                  float* __restrict__ out) {
  constexpr int IU[45] = {0,0,0,0,0,0,0,0,0, 1,1,1,1,1,1,1,1, 2,2,2,2,2,2,2,
                          3,3,3,3,3,3, 4,4,4,4,4, 5,5,5,5, 6,6,6, 7,7, 8};
  constexpr int JU[45] = {0,1,2,3,4,5,6,7,8, 1,2,3,4,5,6,7,8, 2,3,4,5,6,7,8,
                          3,4,5,6,7,8, 4,5,6,7,8, 5,6,7,8, 6,7,8, 7,8, 8};

  const int tid  = threadIdx.x;
  const int wave = tid >> 6;          // 0..7 -> image row r0+wave
  const int lane = tid & 63;
  const int colA = lane & 31;
  const int kg   = lane >> 5;

  // XCD-aware remap (grid 256 = 32 blocks per XCD)
  const int phys = blockIdx.x;
  const int xcd  = phys & 7;
  const int slot = phys >> 3;              // 0..31
  const int g    = xcd * 16 + (slot >> 1); // row-group 0..127
  const int nt   = slot & 1;
  const int b    = g >> 3;
  const int r0   = (g & 7) * 8;

  __shared__ __align__(16) unsigned char smem[LDS_TOTAL];
  const char* BpB = (const char*)Bp;

  f32x16 acc[2] = {};                 // persists across both ks-rounds

  for (int ks = 0; ks < 2; ++ks) {
    __syncthreads();                  // everyone done reading previous B + x

    // ---- stage B-slice (108 frags) async: 13-14 per wave ----------------
    const size_t bSrc = (size_t)(nt * 2 + ks) * 110592;
    for (int f = wave; f < 108; f += 8)
      stage16(BpB + bSrc + (size_t)f * 1024 + lane * 16,
              (char*)smem + BOFF + f * 1024);   // uniform base, HW +lane*16

    // ---- stage x-tile: 10 rows x 66 cols x 32 ch (this ks-half), f16 ----
    for (int idx = tid; idx < 5280; idx += 512) {
      const int row = idx / 528;
      const int rem = idx - row * 528;
      const int col = rem >> 3;
      const int gq  = rem & 7;
      const int hh  = r0 - 1 + row;
      const int ww  = col - 1;
      float4 v = make_float4(0.f, 0.f, 0.f, 0.f);
      if ((unsigned)hh < 64u && (unsigned)ww < 64u)
        v = *(const float4*)(x + ((((size_t)b * 64 + hh) * 64 + ww) * 64
                                  + ks * 32 + gq * 4));
      half4v hv;
      hv[0] = (_Float16)v.x; hv[1] = (_Float16)v.y;
      hv[2] = (_Float16)v.z; hv[3] = (_Float16)v.w;
      const int addr = XOFF + ((row * 4224 + col * 64 + gq * 8)
                               ^ (((col >> 1) & 3) << 4));
      *(half4v*)(smem + addr) = hv;
    }

    asm volatile("s_waitcnt vmcnt(0)" ::: "memory");   // B landed
    __syncthreads();                                    // x writes visible

    half8 tapA[2][9], tapB[2][9];

    // ---- taps for cc=0 ---------------------------------------------------
#pragma unroll
    for (int mt = 0; mt < 2; ++mt)
#pragma unroll
      for (int t = 0; t < 9; ++t) {
        const int xrow = wave + t / 3;
        const int ce   = mt * 32 + colA + (t % 3);
        const int a = XOFF + ((xrow * 4224 + ce * 64 + kg * 16)
                              ^ (((ce >> 1) & 3) << 4));
        tapA[mt][t] = *(const half8*)(smem + a);
      }

    // ---- cc = 0: 54 l-steps; depth-6 bf prefetch; trickle cc=1 taps ------
    {
      const unsigned fb = BOFF + lane * 16;
      half8 bq[6];
#pragma unroll
      for (int q = 0; q < 6; ++q)
        bq[q] = *(const half8*)(smem + fb + q * 1024);
#pragma unroll
      for (int l = 0; l < 54; ++l) {
        const half8 bf = bq[l % 6];
        if (l + 6 < 54)               // compile-time after unroll
          bq[l % 6] = *(const half8*)(smem + fb + (l + 6) * 1024);
        if (l % 3 == 0) {             // 18 trickled tap loads for cc=1
          const int q  = l / 3;
          const int mt = q / 9, tt = q % 9;
          const int xrow = wave + tt / 3;
          const int ce   = mt * 32 + colA + (tt % 3);
          const int a = XOFF + ((xrow * 4224 + ce * 64 + 32 + kg * 16)
                                ^ (((ce >> 1) & 3) << 4));
          tapB[mt][tt] = *(const half8*)(smem + a);
        }
        half8 a0, a1;
        if (l < 45) {
          a0 = tapA[0][IU[l]] * tapA[0][JU[l]];   // v_pk_mul_f16 x4
          a1 = tapA[1][IU[l]] * tapA[1][JU[l]];
        } else {
          a0 = tapA[0][l - 45];
          a1 = tapA[1][l - 45];
        }
        __builtin_amdgcn_s_setprio(1);
        acc[0] = __builtin_amdgcn_mfma_f32_32x32x16_f16(a0, bf, acc[0], 0, 0, 0);
        acc[1] = __builtin_amdgcn_mfma_f32_32x32x16_f16(a1, bf, acc[1], 0, 0, 0);
        __builtin_amdgcn_s_setprio(0);
      }
    }

    // ---- cc = 1: 54 l-steps on tapB --------------------------------------
    {
      const unsigned fb = BOFF + 54 * 1024 + lane * 16;
      half8 bq[6];
#pragma unroll
      for (int q = 0; q < 6; ++q)
        bq[q] = *(const half8*)(smem + fb + q * 1024);
#pragma unroll
      for (int l = 0; l < 54; ++l) {
        const half8 bf = bq[l % 6];
        if (l + 6 < 54)
          bq[l % 6] = *(const half8*)(smem + fb + (l + 6) * 1024);
        half8 a0, a1;
        if (l < 45) {
          a0 = tapB[0][IU[l]] * tapB[0][JU[l]];
          a1 = tapB[1][IU[l]] * tapB[1][JU[l]];
        } else {
          a0 = tapB[0][l - 45];
          a1 = tapB[1][l - 45];
        }
        __builtin_amdgcn_s_setprio(1);
        acc[0] = __builtin_amdgcn_mfma_f32_32x32x16_f16(a0, bf, acc[0], 0, 0, 0);
        acc[1] = __builtin_amdgcn_mfma_f32_32x32x16_f16(a1, bf, acc[1], 0, 0, 0);
        __builtin_amdgcn_s_setprio(0);
      }
    }
  }

  // ---- epilogue: bias + coalesced stores ---------------------------------
  const float bias = ((const float*)(BpB + 442368))[nt * 32 + colA];
#pragma unroll
  for (int mt = 0; mt < 2; ++mt) {
    float* op = out + (((size_t)b * 64 + r0 + wave) * 64 + mt * 32) * 64
                    + nt * 32 + colA;
#pragma unroll
    for (int gi = 0; gi < 16; ++gi) {
      const int rowD = (gi & 3) + 8 * (gi >> 2) + 4 * kg;  // pixel within mt
      op[(size_t)rowD * 64] = acc[mt][gi] + bias;
    }
  }
}

extern "C" void kernel_launch(void* const* d_in, const int* in_sizes, int n_in,
                              void* d_out, int out_size, void* d_ws, size_t ws_size,
                              hipStream_t stream) {
  const float* x = (const float*)d_in[0];
  const float* W = (const float*)d_in[1];
  float* out     = (float*)d_out;
  _Float16* Bp   = (_Float16*)d_ws;   // 442368 B frags + 256 B bias

  prepack_kernel<<<dim3((221248 + 255) / 256), dim3(256), 0, stream>>>(W, Bp);
  qconv_kernel<<<dim3(256), dim3(512), 0, stream>>>(x, Bp, out);
}